// Round 13
// baseline (390.154 us; speedup 1.0000x reference)
//
#include <hip/hip_runtime.h>
#include <hip/hip_bf16.h>

typedef unsigned char u8;
typedef unsigned int u32;
typedef int i32x8 __attribute__((ext_vector_type(8)));
typedef float f32x4 __attribute__((ext_vector_type(4)));

#define NX 8192
#define NY 8192
#define D  512
#define BM 128
#define BN 128
#define BK 128   // fp8 bytes per K-step; one 16x16x128 MFMA spans it

#define SCALE_ONE 0x7F7F7F7F  // E8M0 127 = 2^0 in every byte -> any opsel picks 1.0

// One WAVE per row (16384 rows: first 8192 = x, rest = y). No LDS, no barrier.
// fp32 -> fp8 e4m3 (HW cvt) into ws + exact fp32 squared row norm.
__global__ __launch_bounds__(256) void prep_kernel(
    const float* __restrict__ x, const float* __restrict__ y,
    u8* __restrict__ xq, u8* __restrict__ yq,
    float* __restrict__ x2, float* __restrict__ y2)
{
    const int lane = threadIdx.x & 63;
    const int row  = blockIdx.x * 4 + (threadIdx.x >> 6);
    const float* src; u8* dst; float* nrm;
    if (row < NX) {
        src = x + (size_t)row * D; dst = xq + (size_t)row * D; nrm = x2 + row;
    } else {
        const int r = row - NX;
        src = y + (size_t)r * D; dst = yq + (size_t)r * D; nrm = y2 + r;
    }
    float4 v0 = *(const float4*)(src + lane * 8);
    float4 v1 = *(const float4*)(src + lane * 8 + 4);
    float s = v0.x*v0.x + v0.y*v0.y + v0.z*v0.z + v0.w*v0.w
            + v1.x*v1.x + v1.y*v1.y + v1.z*v1.z + v1.w*v1.w;
    u32 p0 = 0, p1 = 0;
    p0 = __builtin_amdgcn_cvt_pk_fp8_f32(v0.x, v0.y, p0, false);
    p0 = __builtin_amdgcn_cvt_pk_fp8_f32(v0.z, v0.w, p0, true);
    p1 = __builtin_amdgcn_cvt_pk_fp8_f32(v1.x, v1.y, p1, false);
    p1 = __builtin_amdgcn_cvt_pk_fp8_f32(v1.z, v1.w, p1, true);
    uint2 pk = make_uint2(p0, p1);
    *(uint2*)(dst + lane * 8) = pk;

    #pragma unroll
    for (int o = 32; o > 0; o >>= 1) s += __shfl_down(s, o);
    if (lane == 0) *nrm = s;
}

// Barrier-free direct-L2 RBF GEMM. 128x128 tile, 4 waves (2x2 of 64x64),
// mfma_scale 16x16x128 f8f6f4, unit scales. NO LDS, NO __syncthreads:
// each lane loads its 32B A/B fragments straight from global (L1 serves the
// 2x inter-wave reuse; per-K-step tile slices are 16 KB each and L1 is 32 KB).
// The compiler software-pipelines next-step fragment loads under current-step
// MFMAs (nothing fences it), epilogue stores are genuinely fire-and-forget,
// and no data race is possible by construction (pure loads + private acc).
// Fragment indexing is byte-identical to the measured R9 LDS path, with
// As[(r)*BK+ko] replaced by xq[(row0+r)*D + kt*BK + ko].
__global__ __launch_bounds__(256, 2) void rbf_kernel(
    const u8* __restrict__ xq, const u8* __restrict__ yq,
    const float* __restrict__ x2, const float* __restrict__ y2,
    const float* __restrict__ gamma_p, float* __restrict__ out)
{
    const int t    = threadIdx.x;
    const int lane = t & 63;
    const int wid  = t >> 6;          // 0..3
    const int wr   = wid >> 1;        // row half
    const int wc   = wid & 1;         // col half

    // XCD-aware bijective swizzle (nwg = 4096, % 8 == 0)
    const int nwg = gridDim.x;
    const int cpx = nwg >> 3;
    const int bid = blockIdx.x;
    const int swz = (bid & 7) * cpx + (bid >> 3);
    const int brow = swz >> 6;        // 64 x 64 tile grid
    const int bcol = swz & 63;

    const size_t row0 = (size_t)brow * BM;
    const size_t col0 = (size_t)bcol * BN;

    const int ko = (lane >> 4) * 32;  // k-group byte offset within K-step
    const int ar = (lane & 15);

    // per-lane fragment base pointers (advance by BK each K-step)
    const u8* ap[4];
    const u8* bp[4];
    #pragma unroll
    for (int m = 0; m < 4; ++m)
        ap[m] = xq + (row0 + (size_t)(wr * 64 + m * 16 + ar)) * D + ko;
    #pragma unroll
    for (int n = 0; n < 4; ++n)
        bp[n] = yq + (col0 + (size_t)(wc * 64 + n * 16 + ar)) * D + ko;

    f32x4 acc[4][4] = {};

    #pragma unroll
    for (int kt = 0; kt < 4; ++kt) {
        i32x8 a[4], b[4];
        #pragma unroll
        for (int m = 0; m < 4; ++m)
            a[m] = *(const i32x8*)(ap[m] + kt * BK);
        #pragma unroll
        for (int n = 0; n < 4; ++n)
            b[n] = *(const i32x8*)(bp[n] + kt * BK);
        #pragma unroll
        for (int m = 0; m < 4; ++m)
            #pragma unroll
            for (int n = 0; n < 4; ++n)
                acc[m][n] = __builtin_amdgcn_mfma_scale_f32_16x16x128_f8f6f4(
                    a[m], b[n], acc[m][n],
                    0 /*A=fp8*/, 0 /*B=fp8*/,
                    0, SCALE_ONE, 0, SCALE_ONE);
    }

    // epilogue: out[i][j] = exp(-gamma * max(x2[i] + y2[j] - 2*dot, 0))
    const float gamma = *gamma_p;
    const int rl = (lane >> 4) * 4;   // C/D: row = (lane>>4)*4 + reg, col = lane&15
    const int cl = lane & 15;
    #pragma unroll
    for (int m = 0; m < 4; ++m) {
        #pragma unroll
        for (int j = 0; j < 4; ++j) {
            const size_t gr = row0 + wr * 64 + m * 16 + rl + j;
            const float xn = x2[gr];
            float* orow = out + gr * (size_t)NY + col0 + wc * 64 + cl;
            #pragma unroll
            for (int n = 0; n < 4; ++n) {
                const float yn = y2[col0 + wc * 64 + n * 16 + cl];
                float sq = xn + yn - 2.0f * acc[m][n][j];
                sq = fmaxf(sq, 0.0f);
                orow[n * 16] = __expf(-gamma * sq);
            }
        }
    }
}

extern "C" void kernel_launch(void* const* d_in, const int* in_sizes, int n_in,
                              void* d_out, int out_size, void* d_ws, size_t ws_size,
                              hipStream_t stream) {
    const float* x = (const float*)d_in[0];
    const float* y = (const float*)d_in[1];
    const float* gamma_p = (const float*)d_in[2];
    float* out = (float*)d_out;

    // ws layout: xq[8192*512] u8 | yq[8192*512] u8 | x2[8192] f32 | y2[8192] f32
    u8* xq = (u8*)d_ws;
    u8* yq = xq + (size_t)NX * D;
    float* x2 = (float*)(yq + (size_t)NY * D);
    float* y2 = x2 + NX;

    prep_kernel<<<(NX + NY) / 4, 256, 0, stream>>>(x, y, xq, yq, x2, y2);

    const int grid = (NX / BM) * (NY / BN);   // 64 * 64 = 4096
    rbf_kernel<<<grid, 256, 0, stream>>>(xq, yq, x2, y2, gamma_p, out);
}